// Round 2
// baseline (502.099 us; speedup 1.0000x reference)
//
#include <hip/hip_runtime.h>
#include <math.h>

#define L_DIM 8
#define T_DIM 128
#define S_DIM 128
#define SP1   129
#define SPAD  132                      // padded LDS row stride (16-B aligned)
#define BIGF  1000000000.0f
#define EPSF  1e-5f
#define NTHREADS 1024
#define NWAVES 16
#define TCHUNKS 132                    // 2*128*132 floats / 256 floats-per-chunk

// ---- DPP cross-lane reductions on the VALU pipe ----
template<int CTRL>
__device__ __forceinline__ float dpp_add_part(float x) {
    // shifted-in / non-receiving lanes contribute 0 (old=0, bound_ctrl=false)
    int r = __builtin_amdgcn_update_dpp(0, __float_as_int(x), CTRL, 0xF, 0xF, false);
    return __int_as_float(r);
}
// Sum over each 16-lane row; total lands in lane (li==15) of each group.
__device__ __forceinline__ float dpp16Sum15(float x) {
    x += dpp_add_part<0x111>(x);  // row_shr:1
    x += dpp_add_part<0x112>(x);  // row_shr:2
    x += dpp_add_part<0x114>(x);  // row_shr:4
    x += dpp_add_part<0x118>(x);  // row_shr:8
    return x;
}
// Sum over 64 lanes; total lands in lane 63 (wave-0 LN / aff only).
__device__ __forceinline__ float dppSum63(float x) {
    x += dpp_add_part<0x111>(x);
    x += dpp_add_part<0x112>(x);
    x += dpp_add_part<0x114>(x);
    x += dpp_add_part<0x118>(x);
    x += dpp_add_part<0x142>(x);  // row_bcast:15
    x += dpp_add_part<0x143>(x);  // row_bcast:31
    return x;
}
__device__ __forceinline__ float lane63(float x) {
    return __int_as_float(__builtin_amdgcn_readlane(__float_as_int(x), 63));
}

// ---- raw barriers (no vmcnt drain except where stated) ----
__device__ __forceinline__ void wg_bar() {
    asm volatile("s_waitcnt lgkmcnt(0)" ::: "memory");
    __builtin_amdgcn_s_barrier();
    asm volatile("" ::: "memory");
}
__device__ __forceinline__ void wg_bar_vm() {
    asm volatile("s_waitcnt vmcnt(0) lgkmcnt(0)" ::: "memory");
    __builtin_amdgcn_s_barrier();
    asm volatile("" ::: "memory");
}

// async global->LDS, 16B per lane (global_load_lds_dwordx4)
__device__ __forceinline__ void gld_lds16(const float* g, float* l) {
    __builtin_amdgcn_global_load_lds(
        (const __attribute__((address_space(1))) void*)g,
        (__attribute__((address_space(3))) void*)l,
        16, 0, 0);
}

// Stage attn_t[b] q,k (256 rows x 129) into LDS with rows PADDED to 132 floats.
// LDS dest is linear (wave-uniform base + lane*16B); the row padding is achieved
// by pre-swizzling the per-lane GLOBAL source address. Pad cols 129..131 read
// in-bounds garbage (next row / v-matrix) and are never consumed.
__device__ __forceinline__ void stage_t_padded(const float* __restrict__ src,
                                               float* __restrict__ lds,
                                               int wid, int lane) {
#pragma unroll
    for (int k = 0; k < 9; ++k) {
        int c = wid + k * NWAVES;
        if (c < TCHUNKS) {
            int s   = c * 64 + lane;      // 16-B slot id; 33 slots per padded row
            int row = s / 33;
            int w   = s - row * 33;
            gld_lds16(src + (size_t)row * SP1 + w * 4, lds + c * 256);
        }
    }
}

// matvec from padded-LDS matrix: rows r0=wid*8+g and r0+4, 8 elems/thread
__device__ __forceinline__ void mv_ldsT(const float* __restrict__ mat,
                                        const float in[8], int li, int r_base,
                                        float* __restrict__ dst) {
#pragma unroll
    for (int p = 0; p < 2; ++p) {
        int r = r_base + p * 4;
        const float* row = mat + r * SPAD;
        float acc = 0.0f;
#pragma unroll
        for (int e = 0; e < 8; ++e) acc = fmaf(row[li * 8 + e], in[e], acc);
        acc = dpp16Sum15(acc);
        if (li == 15) dst[r] = acc + row[128];
    }
}

// matvec from register-held rows
__device__ __forceinline__ void mv_regs(const float wv[2][8], const float wb[2],
                                        const float in[8], int li, int r_base,
                                        float* __restrict__ dst) {
#pragma unroll
    for (int p = 0; p < 2; ++p) {
        float acc = 0.0f;
#pragma unroll
        for (int e = 0; e < 8; ++e) acc = fmaf(wv[p][e], in[e], acc);
        acc = dpp16Sum15(acc);
        if (li == 15) dst[r_base + p * 4] = acc + wb[p];
    }
}

// prefetch one 128x129 matrix's 2 rows into regs
__device__ __forceinline__ void row_prefetch(const float* __restrict__ mb_,
                                             int li, int r0, int r1,
                                             float arr[2][8], float* b0, float* b1) {
#pragma unroll
    for (int p = 0; p < 2; ++p) {
        int r = p ? r1 : r0;
        const float* row = mb_ + (size_t)r * SP1 + li * 8;
#pragma unroll
        for (int e = 0; e < 8; ++e) arr[p][e] = row[e];
        float bb = mb_[(size_t)r * SP1 + 128];
        if (p) *b1 = bb; else *b0 = bb;
    }
}

// Softmax + @v + residual; group (wid,g) owns rows r0, r0+4; 8 keys/thread.
// No max-reduction: s' = qk*scale - BIG*m_r*(1-m_j) is a row-constant shift of
// the reference scores (softmax-invariant); diagonal j==r is unmasked when
// m_r==1 so den>0 always.
template<bool MASKED>
__device__ __forceinline__ void attn_sm(int li, int r_base,
                                        const float* __restrict__ lds_q,
                                        const float* __restrict__ lds_k,
                                        const float* __restrict__ lds_v,
                                        const float m1mj[8], float mr0, float mr1,
                                        const float* __restrict__ resid,
                                        float* __restrict__ lds_out)
{
    const float scale = 0.08838834764831845f; // rsqrt(128)
    float kx[8], vx[8];
#pragma unroll
    for (int e = 0; e < 8; ++e) { kx[e] = lds_k[li * 8 + e]; vx[e] = lds_v[li * 8 + e]; }
#pragma unroll
    for (int p = 0; p < 2; ++p) {
        int r = r_base + p * 4;
        float qs = lds_q[r] * scale;
        float bp = MASKED ? (BIGF * (p ? mr1 : mr0)) : 0.0f;
        float den = 0.0f, num = 0.0f;
#pragma unroll
        for (int e = 0; e < 8; ++e) {
            float s_ = MASKED ? fmaf(-bp, m1mj[e], qs * kx[e]) : (qs * kx[e]);
            float ee = __expf(s_);
            den += ee;
            num = fmaf(ee, vx[e], num);
        }
        den = dpp16Sum15(den);
        num = dpp16Sum15(num);
        if (li == 15) lds_out[r] = num / den + resid[r];
    }
}

__global__ __launch_bounds__(NTHREADS)
void net_kernel(const float* __restrict__ x,
                const float* __restrict__ W,
                const float* __restrict__ maskp,
                const float* __restrict__ attn_t,
                const float* __restrict__ attn_n,
                const float* __restrict__ norm_params,
                const float* __restrict__ ada,
                float* __restrict__ out,
                unsigned long long* __restrict__ mbox)
{
    const int t    = blockIdx.x;
    const int tid  = threadIdx.x;
    const int lane = tid & 63;
    const int wid  = tid >> 6;
    const int li   = lane & 15;
    const int g    = lane >> 4;
    const int r0   = wid * 8 + g;
    const int r1   = r0 + 4;

    __shared__ float lds_t[2 * S_DIM * SPAD];   // attn_t q,k staged, padded (132 KiB)
    __shared__ float lds_vals[S_DIM];
    __shared__ float lds_q[S_DIM], lds_k[S_DIM], lds_v[S_DIM];
    __shared__ float lds_tv[S_DIM];
    __shared__ float lds_vn[S_DIM];

    float nq[2][8], nk[2][8], nv[2][8];         // n-attn rows (persistent prefetch)
    float nqb0, nqb1, nkb0, nkb1, nvb0, nvb1;

    // ---- prologue: stage attn_t[0] q,k; prefetch attn_n[0][t] rows ----
    {
        const float* srcn = attn_n + (size_t)t * 3 * S_DIM * SP1;
        stage_t_padded(attn_t, lds_t, wid, lane);
        row_prefetch(srcn,                     li, r0, r1, nq, &nqb0, &nqb1);
        row_prefetch(srcn + 1 * S_DIM * SP1,   li, r0, r1, nk, &nkb0, &nkb1);
        row_prefetch(srcn + 2 * S_DIM * SP1,   li, r0, r1, nv, &nvb0, &nvb1);
    }

    for (int b = 0; b < L_DIM; ++b) {
        // ---- aux issue (all waves; lands during the wave-0 poll window) ----
        float tvw[2][8], tvb0, tvb1;            // attn_t[b] v rows (L2-resident)
        row_prefetch(attn_t + ((size_t)b * 3 + 2) * S_DIM * SP1, li, r0, r1,
                     tvw, &tvb0, &tvb1);
        const float* mrow = maskp + (size_t)(b * T_DIM + t) * S_DIM;
        float m1mj[8];
#pragma unroll
        for (int e = 0; e < 8; ++e) m1mj[e] = 1.0f - mrow[li * 8 + e];
        float mr0 = mrow[r0], mr1 = mrow[r1];

        float w0r = 0.f, w1r = 0.f, wb = 0.f, mm0 = 0.f, mm1 = 0.f;
        if (wid == 0) {
            const float* wrow = W + (size_t)(b * T_DIM + t) * SP1;
            w0r = wrow[lane]; w1r = wrow[lane + 64]; wb = wrow[128];
            mm0 = mrow[lane]; mm1 = mrow[lane + 64];
        }

        // ---- 1+2: poll prev outputs + gelu + LayerNorm (wave 0 only) ----
        if (wid == 0) {
            float np00 = norm_params[(b * 2 + 0) * S_DIM + lane];
            float np10 = norm_params[(b * 2 + 0) * S_DIM + lane + 64];
            float np01 = norm_params[(b * 2 + 1) * S_DIM + lane];
            float np11 = norm_params[(b * 2 + 1) * S_DIM + lane + 64];
            float v0, v1;
            if (b == 0) {
                v0 = x[lane]; v1 = x[lane + 64];
            } else {
                float a00 = ada[((b - 1) * T_DIM + lane) * 2 + 0];
                float a01 = ada[((b - 1) * T_DIM + lane) * 2 + 1];
                float a10 = ada[((b - 1) * T_DIM + lane + 64) * 2 + 0];
                float a11 = ada[((b - 1) * T_DIM + lane + 64) * 2 + 1];
                const unsigned long long* mb_ = mbox + (size_t)(b - 1) * T_DIM;
                unsigned long long u0, u1;
                do { u0 = __hip_atomic_load(&mb_[lane], __ATOMIC_RELAXED, __HIP_MEMORY_SCOPE_AGENT); }
                while ((unsigned int)(u0 >> 32) != (unsigned int)b);
                do { u1 = __hip_atomic_load(&mb_[lane + 64], __ATOMIC_RELAXED, __HIP_MEMORY_SCOPE_AGENT); }
                while ((unsigned int)(u1 >> 32) != (unsigned int)b);
                {
                    float z = __uint_as_float((unsigned int)u0) * a00;
                    float z3 = z * z * z;
                    v0 = 0.5f * z * (1.0f + tanhf(0.7978845608028654f * (z + 0.044715f * z3))) * a01;
                }
                {
                    float z = __uint_as_float((unsigned int)u1) * a10;
                    float z3 = z * z * z;
                    v1 = 0.5f * z * (1.0f + tanhf(0.7978845608028654f * (z + 0.044715f * z3))) * a11;
                }
            }
            float s  = dppSum63(v0 + v1);
            float mu = lane63(s) * (1.0f / 128.0f);
            float d0 = v0 - mu, d1 = v1 - mu;
            float s2 = dppSum63(fmaf(d0, d0, d1 * d1));
            float rstd = rsqrtf(lane63(s2) * (1.0f / 128.0f) + EPSF);
            lds_vals[lane]      = d0 * rstd * np00 + np01;
            lds_vals[lane + 64] = d1 * rstd * np10 + np11;
        }
        wg_bar_vm(); // BAR_A: lds_vals ready; drains lds_t stage + all reg prefetch

        // ---- 3: t-attention qkv (q,k from staged LDS; v from regs) ----
        {
            float iv[8];
#pragma unroll
            for (int e = 0; e < 8; ++e) iv[e] = lds_vals[li * 8 + e];
            mv_ldsT(lds_t,                iv, li, r0, lds_q);
            mv_ldsT(lds_t + S_DIM * SPAD, iv, li, r0, lds_k);
            float tb[2] = { tvb0, tvb1 };
            mv_regs(tvw, tb, iv, li, r0, lds_v);
        }
        wg_bar(); // BAR_B

        // ---- stage attn_t[b+1] q,k (lds_t readers all passed BAR_B) ----
        if (b < L_DIM - 1)
            stage_t_padded(attn_t + (size_t)(b + 1) * 3 * S_DIM * SP1, lds_t, wid, lane);

        // ---- 4: t-softmax (unmasked) + residual ----
        attn_sm<false>(li, r0, lds_q, lds_k, lds_v, m1mj, 0.f, 0.f, lds_vals, lds_tv);
        wg_bar(); // BAR_C

        // ---- 5: n-attention qkv fully from regs ----
        {
            float tvv[8];
#pragma unroll
            for (int e = 0; e < 8; ++e) tvv[e] = lds_tv[li * 8 + e];
            float bq[2] = { nqb0, nqb1 }, bk[2] = { nkb0, nkb1 }, bv[2] = { nvb0, nvb1 };
            mv_regs(nq, bq, tvv, li, r0, lds_q);
            mv_regs(nk, bk, tvv, li, r0, lds_k);
            mv_regs(nv, bv, tvv, li, r0, lds_v);
        }

        // ---- prefetch attn_n[b+1][t] rows (regs dead after step 5) ----
        if (b < L_DIM - 1) {
            const float* srcn = attn_n + (size_t)((b + 1) * T_DIM + t) * 3 * S_DIM * SP1;
            row_prefetch(srcn,                   li, r0, r1, nq, &nqb0, &nqb1);
            row_prefetch(srcn + 1 * S_DIM * SP1, li, r0, r1, nk, &nkb0, &nkb1);
            row_prefetch(srcn + 2 * S_DIM * SP1, li, r0, r1, nv, &nvb0, &nvb1);
        }
        wg_bar(); // BAR_D

        // ---- 6: n-softmax (masked) + residual ----
        attn_sm<true>(li, r0, lds_q, lds_k, lds_v, m1mj, mr0, mr1, lds_tv, lds_vn);
        wg_bar(); // BAR_E

        // ---- 7: aff + publish (wave 0 only) ----
        if (wid == 0) {
            float term = w0r * mm0 * lds_vn[lane] + w1r * mm1 * lds_vn[lane + 64];
            float s = dppSum63(term);
            if (lane == 63) {
                float aff = s + wb;
                if (b == L_DIM - 1) {
                    out[t] = aff;
                } else {
                    unsigned long long u =
                        ((unsigned long long)(unsigned int)(b + 1) << 32) |
                        (unsigned long long)__float_as_uint(aff);
                    __hip_atomic_store(&mbox[(size_t)b * T_DIM + t], u,
                                       __ATOMIC_RELAXED, __HIP_MEMORY_SCOPE_AGENT);
                }
            }
        }
        // no trailing barrier: next write to lds_vn is step 6 of b+1 (>=4 barriers
        // away), and wave 0 must pass BAR_A(b+1) before any wave proceeds.
    }
}

extern "C" void kernel_launch(void* const* d_in, const int* in_sizes, int n_in,
                              void* d_out, int out_size, void* d_ws, size_t ws_size,
                              hipStream_t stream) {
    const float* x           = (const float*)d_in[0];
    const float* W           = (const float*)d_in[1];
    const float* maskp       = (const float*)d_in[2];
    const float* attn_t      = (const float*)d_in[3];
    const float* attn_n      = (const float*)d_in[4];
    // d_in[5] = attn_mask_n (67 MB) intentionally unused: recomputed from mask
    const float* norm_params = (const float*)d_in[6];
    const float* ada         = (const float*)d_in[7];
    float* out = (float*)d_out;

    unsigned long long* mbox = (unsigned long long*)d_ws; // 7 epochs x 128 slots x 8B

    hipMemsetAsync(d_ws, 0, (size_t)(L_DIM - 1) * T_DIM * sizeof(unsigned long long), stream);

    void* args[] = { (void*)&x, (void*)&W, (void*)&maskp, (void*)&attn_t, (void*)&attn_n,
                     (void*)&norm_params, (void*)&ada, (void*)&out, (void*)&mbox };
    hipLaunchCooperativeKernel((const void*)net_kernel, dim3(T_DIM), dim3(NTHREADS),
                               args, 0, stream);
}

// Round 3
// 494.824 us; speedup vs baseline: 1.0147x; 1.0147x over previous
//
#include <hip/hip_runtime.h>
#include <math.h>

#define L_DIM 8
#define T_DIM 128
#define S_DIM 128
#define SP1   129
#define SPAD  132                      // padded LDS row stride (16-B aligned)
#define BIGF  1000000000.0f
#define EPSF  1e-5f
#define NTHREADS 1024
#define NWAVES 16
#define TCHUNKS 132                    // 2*128*132 floats / 256 floats-per-chunk

// ---- DPP cross-lane reductions on the VALU pipe ----
template<int CTRL>
__device__ __forceinline__ float dpp_add_part(float x) {
    // shifted-in / non-receiving lanes contribute 0 (old=0, bound_ctrl=false)
    int r = __builtin_amdgcn_update_dpp(0, __float_as_int(x), CTRL, 0xF, 0xF, false);
    return __int_as_float(r);
}
// Sum over each 16-lane row; total lands in lane (li==15) of each group.
__device__ __forceinline__ float dpp16Sum15(float x) {
    x += dpp_add_part<0x111>(x);  // row_shr:1
    x += dpp_add_part<0x112>(x);  // row_shr:2
    x += dpp_add_part<0x114>(x);  // row_shr:4
    x += dpp_add_part<0x118>(x);  // row_shr:8
    return x;
}
// Sum over 64 lanes; total lands in lane 63.
__device__ __forceinline__ float dppSum63(float x) {
    x += dpp_add_part<0x111>(x);
    x += dpp_add_part<0x112>(x);
    x += dpp_add_part<0x114>(x);
    x += dpp_add_part<0x118>(x);
    x += dpp_add_part<0x142>(x);  // row_bcast:15
    x += dpp_add_part<0x143>(x);  // row_bcast:31
    return x;
}
__device__ __forceinline__ float lane63(float x) {
    return __int_as_float(__builtin_amdgcn_readlane(__float_as_int(x), 63));
}

// ---- raw barriers (no vmcnt drain except where stated) ----
__device__ __forceinline__ void wg_bar() {
    asm volatile("s_waitcnt lgkmcnt(0)" ::: "memory");
    __builtin_amdgcn_s_barrier();
    asm volatile("" ::: "memory");
}
__device__ __forceinline__ void wg_bar_vm() {
    asm volatile("s_waitcnt vmcnt(0) lgkmcnt(0)" ::: "memory");
    __builtin_amdgcn_s_barrier();
    asm volatile("" ::: "memory");
}

// async global->LDS, 16B per lane (global_load_lds_dwordx4)
__device__ __forceinline__ void gld_lds16(const float* g, float* l) {
    __builtin_amdgcn_global_load_lds(
        (const __attribute__((address_space(1))) void*)g,
        (__attribute__((address_space(3))) void*)l,
        16, 0, 0);
}

// Stage attn_t[b] q,k (256 rows x 129) into LDS with rows PADDED to 132 floats.
// LDS dest is linear (wave-uniform base + lane*16B); the padding is achieved by
// pre-swizzling the per-lane GLOBAL source address. Pad cols 129..131 hold
// in-bounds garbage (next row) and are never consumed.
__device__ __forceinline__ void stage_t_padded(const float* __restrict__ src,
                                               float* __restrict__ lds,
                                               int wid, int lane) {
#pragma unroll
    for (int k = 0; k < 9; ++k) {
        int c = wid + k * NWAVES;
        if (c < TCHUNKS) {
            int s   = c * 64 + lane;      // 16-B slot id; 33 slots per padded row
            int row = s / 33;
            int w   = s - row * 33;
            gld_lds16(src + (size_t)row * SP1 + w * 4, lds + c * 256);
        }
    }
}

// matvec from padded-LDS matrix: rows r_base and r_base+4, 8 elems/thread
__device__ __forceinline__ void mv_ldsT(const float* __restrict__ mat,
                                        const float in[8], int li, int r_base,
                                        float* __restrict__ dst) {
#pragma unroll
    for (int p = 0; p < 2; ++p) {
        int r = r_base + p * 4;
        const float* row = mat + r * SPAD;
        float acc = 0.0f;
#pragma unroll
        for (int e = 0; e < 8; ++e) acc = fmaf(row[li * 8 + e], in[e], acc);
        acc = dpp16Sum15(acc);
        if (li == 15) dst[r] = acc + row[128];
    }
}

// matvec from register-held rows
__device__ __forceinline__ void mv_regs(const float wv[2][8], const float wb[2],
                                        const float in[8], int li, int r_base,
                                        float* __restrict__ dst) {
#pragma unroll
    for (int p = 0; p < 2; ++p) {
        float acc = 0.0f;
#pragma unroll
        for (int e = 0; e < 8; ++e) acc = fmaf(wv[p][e], in[e], acc);
        acc = dpp16Sum15(acc);
        if (li == 15) dst[r_base + p * 4] = acc + wb[p];
    }
}

// prefetch one 128x129 matrix's 2 rows into regs
__device__ __forceinline__ void row_prefetch(const float* __restrict__ mb_,
                                             int li, int r0, int r1,
                                             float arr[2][8], float* b0, float* b1) {
#pragma unroll
    for (int p = 0; p < 2; ++p) {
        int r = p ? r1 : r0;
        const float* row = mb_ + (size_t)r * SP1 + li * 8;
#pragma unroll
        for (int e = 0; e < 8; ++e) arr[p][e] = row[e];
        float bb = mb_[(size_t)r * SP1 + 128];
        if (p) *b1 = bb; else *b0 = bb;
    }
}

// Softmax + @v + residual; group (wid,g) owns rows r_base, r_base+4; 8 keys/thread.
// No max-reduction: s' = qk*scale - BIG*m_r*(1-m_j) is a row-constant shift of
// the reference scores (softmax-invariant); diagonal j==r is unmasked when
// m_r==1 so den>0 always.
template<bool MASKED>
__device__ __forceinline__ void attn_sm(int li, int r_base,
                                        const float* __restrict__ lds_q,
                                        const float* __restrict__ lds_k,
                                        const float* __restrict__ lds_v,
                                        const float m1mj[8], float mr0, float mr1,
                                        const float* __restrict__ resid,
                                        float* __restrict__ lds_out)
{
    const float scale = 0.08838834764831845f; // rsqrt(128)
    float kx[8], vx[8];
#pragma unroll
    for (int e = 0; e < 8; ++e) { kx[e] = lds_k[li * 8 + e]; vx[e] = lds_v[li * 8 + e]; }
#pragma unroll
    for (int p = 0; p < 2; ++p) {
        int r = r_base + p * 4;
        float qs = lds_q[r] * scale;
        float bp = MASKED ? (BIGF * (p ? mr1 : mr0)) : 0.0f;
        float den = 0.0f, num = 0.0f;
#pragma unroll
        for (int e = 0; e < 8; ++e) {
            float s_ = MASKED ? fmaf(-bp, m1mj[e], qs * kx[e]) : (qs * kx[e]);
            float ee = __expf(s_);
            den += ee;
            num = fmaf(ee, vx[e], num);
        }
        den = dpp16Sum15(den);
        num = dpp16Sum15(num);
        if (li == 15) lds_out[r] = num / den + resid[r];
    }
}

__global__ __launch_bounds__(NTHREADS, 4)   // waves/EU=4 -> VGPR cap 128 (kill spills)
void net_kernel(const float* __restrict__ x,
                const float* __restrict__ W,
                const float* __restrict__ maskp,
                const float* __restrict__ attn_t,
                const float* __restrict__ attn_n,
                const float* __restrict__ norm_params,
                const float* __restrict__ ada,
                float* __restrict__ out,
                unsigned long long* __restrict__ mbox)
{
    const int t    = blockIdx.x;
    const int tid  = threadIdx.x;
    const int lane = tid & 63;
    const int wid  = tid >> 6;
    const int li   = lane & 15;
    const int g    = lane >> 4;
    const int r0   = wid * 8 + g;
    const int r1   = r0 + 4;

    __shared__ float lds_t[2 * S_DIM * SPAD];    // attn_t q,k staged, padded (132 KiB)
    __shared__ float lds_vw[NWAVES * S_DIM];     // per-wave private LN'd vals strips
    __shared__ float lds_q[S_DIM], lds_k[S_DIM], lds_v[S_DIM];
    __shared__ float lds_tv[S_DIM];
    __shared__ float lds_vn[S_DIM];

    float nq[2][8], nk[2][8], nv[2][8];          // n-attn rows (persistent prefetch)
    float nqb0, nqb1, nkb0, nkb1, nvb0, nvb1;

    // ---- prologue: stage attn_t[0] q,k; prefetch attn_n[0][t] rows ----
    {
        const float* srcn = attn_n + (size_t)t * 3 * S_DIM * SP1;
        stage_t_padded(attn_t, lds_t, wid, lane);
        row_prefetch(srcn,                   li, r0, r1, nq, &nqb0, &nqb1);
        row_prefetch(srcn + 1 * S_DIM * SP1, li, r0, r1, nk, &nkb0, &nkb1);
        row_prefetch(srcn + 2 * S_DIM * SP1, li, r0, r1, nv, &nvb0, &nvb1);
    }

    float* vw = lds_vw + wid * S_DIM;            // this wave's private strip

    for (int b = 0; b < L_DIM; ++b) {
        // ---- top barrier: drains staging(b) + reg prefetch(b) issued last layer.
        //      Crossed BEFORE the poll => sits in dead-wait time, not the hot path.
        wg_bar_vm();

        // ---- aux issue for this layer (lands during the poll window) ----
        float tvw[2][8], tvb0, tvb1;             // attn_t[b] v rows (L2-resident)
        row_prefetch(attn_t + ((size_t)b * 3 + 2) * S_DIM * SP1, li, r0, r1,
                     tvw, &tvb0, &tvb1);
        const float* mrow = maskp + (size_t)(b * T_DIM + t) * S_DIM;
        float m1mj[8];
#pragma unroll
        for (int e = 0; e < 8; ++e) m1mj[e] = 1.0f - mrow[li * 8 + e];
        float mr0 = mrow[r0], mr1 = mrow[r1];

        float w0r = 0.f, w1r = 0.f, wb = 0.f, mm0 = 0.f, mm1 = 0.f;
        if (wid == 0) {
            const float* wrow = W + (size_t)(b * T_DIM + t) * SP1;
            w0r = wrow[lane]; w1r = wrow[lane + 64]; wb = wrow[128];
            mm0 = mrow[lane]; mm1 = mrow[lane + 64];
        }

        // ---- 1+2: poll prev outputs + gelu + LayerNorm — ALL waves, redundantly
        //      (bitwise-identical ops => identical results). Each wave writes its
        //      private strip; no barrier between LN and t-qkv. ----
        {
            float np00 = norm_params[(b * 2 + 0) * S_DIM + lane];
            float np10 = norm_params[(b * 2 + 0) * S_DIM + lane + 64];
            float np01 = norm_params[(b * 2 + 1) * S_DIM + lane];
            float np11 = norm_params[(b * 2 + 1) * S_DIM + lane + 64];
            float v0, v1;
            if (b == 0) {
                v0 = x[lane]; v1 = x[lane + 64];
            } else {
                float a00 = ada[((b - 1) * T_DIM + lane) * 2 + 0];
                float a01 = ada[((b - 1) * T_DIM + lane) * 2 + 1];
                float a10 = ada[((b - 1) * T_DIM + lane + 64) * 2 + 0];
                float a11 = ada[((b - 1) * T_DIM + lane + 64) * 2 + 1];
                const unsigned long long* mb_ = mbox + (size_t)(b - 1) * T_DIM;
                unsigned long long u0, u1;
                do { u0 = __hip_atomic_load(&mb_[lane], __ATOMIC_RELAXED, __HIP_MEMORY_SCOPE_AGENT); }
                while ((unsigned int)(u0 >> 32) != (unsigned int)b);
                do { u1 = __hip_atomic_load(&mb_[lane + 64], __ATOMIC_RELAXED, __HIP_MEMORY_SCOPE_AGENT); }
                while ((unsigned int)(u1 >> 32) != (unsigned int)b);
                {
                    float z = __uint_as_float((unsigned int)u0) * a00;
                    float z3 = z * z * z;
                    v0 = 0.5f * z * (1.0f + tanhf(0.7978845608028654f * (z + 0.044715f * z3))) * a01;
                }
                {
                    float z = __uint_as_float((unsigned int)u1) * a10;
                    float z3 = z * z * z;
                    v1 = 0.5f * z * (1.0f + tanhf(0.7978845608028654f * (z + 0.044715f * z3))) * a11;
                }
            }
            float s  = dppSum63(v0 + v1);
            float mu = lane63(s) * (1.0f / 128.0f);
            float d0 = v0 - mu, d1 = v1 - mu;
            float s2 = dppSum63(fmaf(d0, d0, d1 * d1));
            float rstd = rsqrtf(lane63(s2) * (1.0f / 128.0f) + EPSF);
            vw[lane]      = d0 * rstd * np00 + np01;
            vw[lane + 64] = d1 * rstd * np10 + np11;
        }

        // ---- 3: t-attention qkv (q,k from staged LDS; v from regs) ----
        {
            float iv[8];
#pragma unroll
            for (int e = 0; e < 8; ++e) iv[e] = vw[li * 8 + e];
            mv_ldsT(lds_t,                iv, li, r0, lds_q);
            mv_ldsT(lds_t + S_DIM * SPAD, iv, li, r0, lds_k);
            float tb[2] = { tvb0, tvb1 };
            mv_regs(tvw, tb, iv, li, r0, lds_v);
        }
        wg_bar(); // BAR_B

        // ---- stage attn_t[b+1] q,k (lds_t readers all passed BAR_B) ----
        if (b < L_DIM - 1)
            stage_t_padded(attn_t + (size_t)(b + 1) * 3 * S_DIM * SP1, lds_t, wid, lane);

        // ---- 4: t-softmax (unmasked) + residual (own-strip resid) ----
        attn_sm<false>(li, r0, lds_q, lds_k, lds_v, m1mj, 0.f, 0.f, vw, lds_tv);
        wg_bar(); // BAR_C

        // ---- 5: n-attention qkv fully from regs ----
        {
            float tvv[8];
#pragma unroll
            for (int e = 0; e < 8; ++e) tvv[e] = lds_tv[li * 8 + e];
            float bq[2] = { nqb0, nqb1 }, bk[2] = { nkb0, nkb1 }, bv[2] = { nvb0, nvb1 };
            mv_regs(nq, bq, tvv, li, r0, lds_q);
            mv_regs(nk, bk, tvv, li, r0, lds_k);
            mv_regs(nv, bv, tvv, li, r0, lds_v);
        }

        // ---- prefetch attn_n[b+1][t] rows (regs dead after step 5) ----
        if (b < L_DIM - 1) {
            const float* srcn = attn_n + (size_t)((b + 1) * T_DIM + t) * 3 * S_DIM * SP1;
            row_prefetch(srcn,                   li, r0, r1, nq, &nqb0, &nqb1);
            row_prefetch(srcn + 1 * S_DIM * SP1, li, r0, r1, nk, &nkb0, &nkb1);
            row_prefetch(srcn + 2 * S_DIM * SP1, li, r0, r1, nv, &nvb0, &nvb1);
        }
        wg_bar(); // BAR_D

        // ---- 6: n-softmax (masked) + residual ----
        attn_sm<true>(li, r0, lds_q, lds_k, lds_v, m1mj, mr0, mr1, lds_tv, lds_vn);
        wg_bar(); // BAR_E

        // ---- 7: aff + publish (wave 0 only; others run ahead to next layer) ----
        if (wid == 0) {
            float term = w0r * mm0 * lds_vn[lane] + w1r * mm1 * lds_vn[lane + 64];
            float s = dppSum63(term);
            if (lane == 63) {
                float aff = s + wb;
                if (b == L_DIM - 1) {
                    out[t] = aff;
                } else {
                    unsigned long long u =
                        ((unsigned long long)(unsigned int)(b + 1) << 32) |
                        (unsigned long long)__float_as_uint(aff);
                    __hip_atomic_store(&mbox[(size_t)b * T_DIM + t], u,
                                       __ATOMIC_RELAXED, __HIP_MEMORY_SCOPE_AGENT);
                }
            }
        }
        // lds_vn WAR: wave0 reads complete before it reaches next layer's top
        // barrier, which all waves must pass before step 6 of b+1 rewrites it.
    }
}

extern "C" void kernel_launch(void* const* d_in, const int* in_sizes, int n_in,
                              void* d_out, int out_size, void* d_ws, size_t ws_size,
                              hipStream_t stream) {
    const float* x           = (const float*)d_in[0];
    const float* W           = (const float*)d_in[1];
    const float* maskp       = (const float*)d_in[2];
    const float* attn_t      = (const float*)d_in[3];
    const float* attn_n      = (const float*)d_in[4];
    // d_in[5] = attn_mask_n (67 MB) intentionally unused: recomputed from mask
    const float* norm_params = (const float*)d_in[6];
    const float* ada         = (const float*)d_in[7];
    float* out = (float*)d_out;

    unsigned long long* mbox = (unsigned long long*)d_ws; // 7 epochs x 128 slots x 8B

    hipMemsetAsync(d_ws, 0, (size_t)(L_DIM - 1) * T_DIM * sizeof(unsigned long long), stream);

    void* args[] = { (void*)&x, (void*)&W, (void*)&maskp, (void*)&attn_t, (void*)&attn_n,
                     (void*)&norm_params, (void*)&ada, (void*)&out, (void*)&mbox };
    hipLaunchCooperativeKernel((const void*)net_kernel, dim3(T_DIM), dim3(NTHREADS),
                               args, 0, stream);
}

// Round 5
// 427.348 us; speedup vs baseline: 1.1749x; 1.1579x over previous
//
#include <hip/hip_runtime.h>
#include <math.h>

#define L_DIM 8
#define T_DIM 128
#define S_DIM 128
#define SP1   129
#define SPAD  132                      // padded LDS row stride (16-B aligned)
#define BIGF  1000000000.0f
#define EPSF  1e-5f
#define NTHREADS 1024
#define NWAVES 16
#define NCHUNKS 132                    // staged n q,k: 2*128*SPAD floats / 256

// ---- DPP cross-lane reductions on the VALU pipe ----
template<int CTRL>
__device__ __forceinline__ float dpp_add_part(float x) {
    // shifted-in / non-receiving lanes contribute 0 (old=0, bound_ctrl=false)
    int r = __builtin_amdgcn_update_dpp(0, __float_as_int(x), CTRL, 0xF, 0xF, false);
    return __int_as_float(r);
}
// Sum over each 16-lane row; total lands in lane (li==15) of each group.
__device__ __forceinline__ float dpp16Sum15(float x) {
    x += dpp_add_part<0x111>(x);  // row_shr:1
    x += dpp_add_part<0x112>(x);  // row_shr:2
    x += dpp_add_part<0x114>(x);  // row_shr:4
    x += dpp_add_part<0x118>(x);  // row_shr:8
    return x;
}
// Sum over 64 lanes; total lands in lane 63.
__device__ __forceinline__ float dppSum63(float x) {
    x += dpp_add_part<0x111>(x);
    x += dpp_add_part<0x112>(x);
    x += dpp_add_part<0x114>(x);
    x += dpp_add_part<0x118>(x);
    x += dpp_add_part<0x142>(x);  // row_bcast:15
    x += dpp_add_part<0x143>(x);  // row_bcast:31
    return x;
}
__device__ __forceinline__ float lane63(float x) {
    return __int_as_float(__builtin_amdgcn_readlane(__float_as_int(x), 63));
}

// ---- raw barriers (no vmcnt drain except where stated) ----
__device__ __forceinline__ void wg_bar() {
    asm volatile("s_waitcnt lgkmcnt(0)" ::: "memory");
    __builtin_amdgcn_s_barrier();
    asm volatile("" ::: "memory");
}
__device__ __forceinline__ void wg_bar_vm() {
    asm volatile("s_waitcnt vmcnt(0) lgkmcnt(0)" ::: "memory");
    __builtin_amdgcn_s_barrier();
    asm volatile("" ::: "memory");
}

// async global->LDS, 16B per lane (global_load_lds_dwordx4); counts on vmcnt
__device__ __forceinline__ void gld_lds16(const float* g, float* l) {
    __builtin_amdgcn_global_load_lds(
        (const __attribute__((address_space(1))) void*)g,
        (__attribute__((address_space(3))) void*)l,
        16, 0, 0);
}

// Stage attn_n[b][t] q,k (2 x 128 rows x 129 floats) into LDS with rows PADDED
// to 132 floats. LDS dest is linear (wave-uniform base + lane*16B); padding is
// achieved by pre-swizzling the per-lane GLOBAL source address. Pad cols
// 129..131 hold in-bounds garbage (next row / v-matrix) and are never consumed.
// Zero VGPR cost for the payload: data never touches registers.
__device__ __forceinline__ void stage_nqk(const float* __restrict__ src,
                                          float* __restrict__ lds,
                                          int wid, int lane) {
#pragma unroll
    for (int k = 0; k < 9; ++k) {
        int c = wid + k * NWAVES;
        if (c < NCHUNKS) {
            int s   = c * 64 + lane;      // 16-B slot id; 33 slots per padded row
            int row = s / 33;
            int w   = s - row * 33;
            gld_lds16(src + (size_t)row * SP1 + w * 4, lds + c * 256);
        }
    }
}

// matvec rows r_base, r_base+4 straight from GLOBAL (L2/L3-resident attn_t).
// With 16-lane groups the WG covers all 128 rows exactly once: no redundancy.
__device__ __forceinline__ void mv_glb(const float* __restrict__ mat,
                                       const float in[8], int li, int r_base,
                                       float* __restrict__ dst) {
#pragma unroll
    for (int p = 0; p < 2; ++p) {
        int r = r_base + p * 4;
        const float* row = mat + (size_t)r * SP1;
        float acc = 0.0f;
#pragma unroll
        for (int e = 0; e < 8; ++e) acc = fmaf(row[li * 8 + e], in[e], acc);
        acc = dpp16Sum15(acc);
        if (li == 15) dst[r] = acc + row[128];
    }
}

// matvec from the padded staged-LDS matrix (stride SPAD, 16-B aligned rows)
__device__ __forceinline__ void mv_stage(const float* __restrict__ mat,
                                         const float in[8], int li, int r_base,
                                         float* __restrict__ dst) {
#pragma unroll
    for (int p = 0; p < 2; ++p) {
        int r = r_base + p * 4;
        const float* row = mat + r * SPAD;
        float acc = 0.0f;
#pragma unroll
        for (int e = 0; e < 8; ++e) acc = fmaf(row[li * 8 + e], in[e], acc);
        acc = dpp16Sum15(acc);
        if (li == 15) dst[r] = acc + row[128];
    }
}

// matvec from register-held rows (n-attn v only: 18 persistent VGPRs)
__device__ __forceinline__ void mv_regs(const float wv[2][8], const float wb[2],
                                        const float in[8], int li, int r_base,
                                        float* __restrict__ dst) {
#pragma unroll
    for (int p = 0; p < 2; ++p) {
        float acc = 0.0f;
#pragma unroll
        for (int e = 0; e < 8; ++e) acc = fmaf(wv[p][e], in[e], acc);
        acc = dpp16Sum15(acc);
        if (li == 15) dst[r_base + p * 4] = acc + wb[p];
    }
}

// prefetch one 128x129 matrix's 2 rows into regs
__device__ __forceinline__ void row_prefetch(const float* __restrict__ mb_,
                                             int li, int r0, int r1,
                                             float arr[2][8], float* b0, float* b1) {
#pragma unroll
    for (int p = 0; p < 2; ++p) {
        int r = p ? r1 : r0;
        const float* row = mb_ + (size_t)r * SP1 + li * 8;
#pragma unroll
        for (int e = 0; e < 8; ++e) arr[p][e] = row[e];
        float bb = mb_[(size_t)r * SP1 + 128];
        if (p) *b1 = bb; else *b0 = bb;
    }
}

// t-softmax + @v + residual; group (wid,g) owns rows r_base, r_base+4.
// No max-reduction (unmasked scores are row-shift-invariant; exp of bounded qk).
__device__ __forceinline__ void attn_sm_t(int li, int r_base,
                                          const float* __restrict__ lds_q,
                                          const float* __restrict__ lds_k,
                                          const float* __restrict__ lds_v,
                                          const float* __restrict__ resid,
                                          float* __restrict__ lds_out)
{
    const float scale = 0.08838834764831845f; // rsqrt(128)
    float kx[8], vx[8];
#pragma unroll
    for (int e = 0; e < 8; ++e) { kx[e] = lds_k[li * 8 + e]; vx[e] = lds_v[li * 8 + e]; }
#pragma unroll
    for (int p = 0; p < 2; ++p) {
        int r = r_base + p * 4;
        float qs = lds_q[r] * scale;
        float den = 0.0f, num = 0.0f;
#pragma unroll
        for (int e = 0; e < 8; ++e) {
            float ee = __expf(qs * kx[e]);
            den += ee;
            num = fmaf(ee, vx[e], num);
        }
        den = dpp16Sum15(den);
        num = dpp16Sum15(num);
        if (li == 15) lds_out[r] = num / den + resid[r];
    }
}

__global__ __launch_bounds__(NTHREADS)
void net_kernel(const float* __restrict__ x,
                const float* __restrict__ W,
                const float* __restrict__ maskp,
                const float* __restrict__ attn_t,
                const float* __restrict__ attn_n,
                const float* __restrict__ norm_params,
                const float* __restrict__ ada,
                float* __restrict__ out,
                unsigned long long* __restrict__ mbox)
{
    const int t    = blockIdx.x;
    const int tid  = threadIdx.x;
    const int lane = tid & 63;
    const int wid  = tid >> 6;
    const int li   = lane & 15;
    const int g    = lane >> 4;
    const int r0   = wid * 8 + g;
    const int r1   = r0 + 4;

    __shared__ float lds_nqk[2 * S_DIM * SPAD];  // staged attn_n q,k (132 KiB)
    __shared__ float lds_vw[NWAVES * S_DIM];     // per-wave private LN'd strips (8 KiB)
    __shared__ float lds_q[S_DIM], lds_k[S_DIM], lds_v[S_DIM];
    __shared__ float lds_tv[S_DIM];
    __shared__ float lds_aff[NWAVES];

    float nv[2][8];                              // n-attn v rows: the ONLY big
    float nvb0, nvb1;                            // persistent register state

    // ---- prologue: stage attn_n[0][t] q,k; prefetch its v rows ----
    {
        const float* srcn = attn_n + (size_t)t * 3 * S_DIM * SP1;
        stage_nqk(srcn, lds_nqk, wid, lane);
        row_prefetch(srcn + 2 * S_DIM * SP1, li, r0, r1, nv, &nvb0, &nvb1);
    }

    float* vw = lds_vw + wid * S_DIM;            // this wave's private strip

    for (int b = 0; b < L_DIM; ++b) {
        // ---- per-layer aux loads (all L2/L3-resident; issued before the poll) ----
        const float* mrow = maskp + (size_t)(b * T_DIM + t) * S_DIM;
        const float* wrow = W + (size_t)(b * T_DIM + t) * SP1;
        float m1mj[8];
#pragma unroll
        for (int e = 0; e < 8; ++e) m1mj[e] = 1.0f - mrow[li * 8 + e];
        float mr0 = mrow[r0], mr1 = mrow[r1];
        float wr0 = wrow[r0], wr1 = wrow[r1];
        float wb  = (wid == 0) ? wrow[128] : 0.0f;

        // ---- 1+2: poll prev outputs + gelu + LayerNorm — ALL waves redundantly
        //      (bitwise-identical ops => identical results). Each wave writes its
        //      private strip; no barrier between LN and t-qkv. ----
        {
            float np00 = norm_params[(b * 2 + 0) * S_DIM + lane];
            float np10 = norm_params[(b * 2 + 0) * S_DIM + lane + 64];
            float np01 = norm_params[(b * 2 + 1) * S_DIM + lane];
            float np11 = norm_params[(b * 2 + 1) * S_DIM + lane + 64];
            float v0, v1;
            if (b == 0) {
                v0 = x[lane]; v1 = x[lane + 64];
            } else {
                float a00 = ada[((b - 1) * T_DIM + lane) * 2 + 0];
                float a01 = ada[((b - 1) * T_DIM + lane) * 2 + 1];
                float a10 = ada[((b - 1) * T_DIM + lane + 64) * 2 + 0];
                float a11 = ada[((b - 1) * T_DIM + lane + 64) * 2 + 1];
                const unsigned long long* mb_ = mbox + (size_t)(b - 1) * T_DIM;
                unsigned long long u0, u1;
                do { u0 = __hip_atomic_load(&mb_[lane], __ATOMIC_RELAXED, __HIP_MEMORY_SCOPE_AGENT); }
                while ((unsigned int)(u0 >> 32) != (unsigned int)b);
                do { u1 = __hip_atomic_load(&mb_[lane + 64], __ATOMIC_RELAXED, __HIP_MEMORY_SCOPE_AGENT); }
                while ((unsigned int)(u1 >> 32) != (unsigned int)b);
                {
                    float z = __uint_as_float((unsigned int)u0) * a00;
                    float z3 = z * z * z;
                    v0 = 0.5f * z * (1.0f + tanhf(0.7978845608028654f * (z + 0.044715f * z3))) * a01;
                }
                {
                    float z = __uint_as_float((unsigned int)u1) * a10;
                    float z3 = z * z * z;
                    v1 = 0.5f * z * (1.0f + tanhf(0.7978845608028654f * (z + 0.044715f * z3))) * a11;
                }
            }
            float s  = dppSum63(v0 + v1);
            float mu = lane63(s) * (1.0f / 128.0f);
            float d0 = v0 - mu, d1 = v1 - mu;
            float s2 = dppSum63(fmaf(d0, d0, d1 * d1));
            float rstd = rsqrtf(lane63(s2) * (1.0f / 128.0f) + EPSF);
            vw[lane]      = d0 * rstd * np00 + np01;
            vw[lane + 64] = d1 * rstd * np10 + np11;
        }

        // ---- 3: t-attention qkv — rows straight from L2 (no staging, no
        //      long-lived regs; each row read exactly once per WG) ----
        {
            float iv[8];
#pragma unroll
            for (int e = 0; e < 8; ++e) iv[e] = vw[li * 8 + e];
            const float* bb = attn_t + (size_t)b * 3 * S_DIM * SP1;
            mv_glb(bb,                    iv, li, r0, lds_q);
            mv_glb(bb + 1 * S_DIM * SP1,  iv, li, r0, lds_k);
            mv_glb(bb + 2 * S_DIM * SP1,  iv, li, r0, lds_v);
        }
        wg_bar(); // BAR_B

        // ---- 4: t-softmax (unmasked) + residual (own-strip resid) ----
        attn_sm_t(li, r0, lds_q, lds_k, lds_v, vw, lds_tv);
        wg_bar_vm(); // BAR_C: the one vmcnt drain — staged n q,k for b now visible

        // ---- 5: n-attention qkv: q,k from staged LDS, v from regs ----
        {
            float tvv[8];
#pragma unroll
            for (int e = 0; e < 8; ++e) tvv[e] = lds_tv[li * 8 + e];
            mv_stage(lds_nqk,                 tvv, li, r0, lds_q);
            mv_stage(lds_nqk + S_DIM * SPAD,  tvv, li, r0, lds_k);
            float bv[2] = { nvb0, nvb1 };
            mv_regs(nv, bv, tvv, li, r0, lds_v);
        }
        wg_bar(); // BAR_D: n-qkv visible; lds_nqk readers done -> safe to restage

        // ---- stage layer b+1's n q,k + prefetch its v rows; in flight across
        //      n-softmax, aff, publish, poll, LN, t-attn -> drained at BAR_C(b+1)
        if (b < L_DIM - 1) {
            const float* srcn = attn_n + (size_t)((b + 1) * T_DIM + t) * 3 * S_DIM * SP1;
            stage_nqk(srcn, lds_nqk, wid, lane);
            row_prefetch(srcn + 2 * S_DIM * SP1, li, r0, r1, nv, &nvb0, &nvb1);
        }

        // ---- 6: n-softmax (masked) + residual, FUSED with aff partial ----
        {
            const float scale = 0.08838834764831845f;
            float kx[8], vx[8];
#pragma unroll
            for (int e = 0; e < 8; ++e) { kx[e] = lds_k[li * 8 + e]; vx[e] = lds_v[li * 8 + e]; }
            float o0 = 0.0f, o1 = 0.0f;
#pragma unroll
            for (int p = 0; p < 2; ++p) {
                int r = r0 + p * 4;
                float qs = lds_q[r] * scale;
                float bp = BIGF * (p ? mr1 : mr0);
                float den = 0.0f, num = 0.0f;
#pragma unroll
                for (int e = 0; e < 8; ++e) {
                    float s_ = fmaf(-bp, m1mj[e], qs * kx[e]);
                    float ee = __expf(s_);
                    den += ee;
                    num = fmaf(ee, vx[e], num);
                }
                den = dpp16Sum15(den);
                num = dpp16Sum15(num);
                float o = num / den + lds_tv[r];  // valid in owner lane li==15
                if (p) o1 = o; else o0 = o;
            }
            // aff partial: vn feeds ONLY the einsum -> fold it here, skip lds_vn
            float part = (li == 15) ? (wr0 * mr0 * o0 + wr1 * mr1 * o1) : 0.0f;
            part = dppSum63(part);
            if (lane == 63) lds_aff[wid] = part;
        }
        wg_bar(); // BAR_E

        // ---- 7: final aff reduce + publish (wave 0; others run ahead) ----
        if (wid == 0) {
            float pa = (lane < NWAVES) ? lds_aff[lane] : 0.0f;
            pa = dppSum63(pa);
            if (lane == 63) {
                float aff = pa + wb;
                if (b == L_DIM - 1) {
                    out[t] = aff;
                } else {
                    unsigned long long u =
                        ((unsigned long long)(unsigned int)(b + 1) << 32) |
                        (unsigned long long)__float_as_uint(aff);
                    __hip_atomic_store(&mbox[(size_t)b * T_DIM + t], u,
                                       __ATOMIC_RELAXED, __HIP_MEMORY_SCOPE_AGENT);
                }
            }
        }
        // lds_aff WAR: rewritten only at step 6 of b+1, which is after BAR_D(b+1);
        // wave 0's reads complete before it can pass BAR_B(b+1).
    }
}

extern "C" void kernel_launch(void* const* d_in, const int* in_sizes, int n_in,
                              void* d_out, int out_size, void* d_ws, size_t ws_size,
                              hipStream_t stream) {
    const float* x           = (const float*)d_in[0];
    const float* W           = (const float*)d_in[1];
    const float* maskp       = (const float*)d_in[2];
    const float* attn_t      = (const float*)d_in[3];
    const float* attn_n      = (const float*)d_in[4];
    // d_in[5] = attn_mask_n (67 MB) intentionally unused: recomputed from mask
    const float* norm_params = (const float*)d_in[6];
    const float* ada         = (const float*)d_in[7];
    float* out = (float*)d_out;

    unsigned long long* mbox = (unsigned long long*)d_ws; // 7 epochs x 128 slots x 8B

    hipMemsetAsync(d_ws, 0, (size_t)(L_DIM - 1) * T_DIM * sizeof(unsigned long long), stream);

    void* args[] = { (void*)&x, (void*)&W, (void*)&maskp, (void*)&attn_t, (void*)&attn_n,
                     (void*)&norm_params, (void*)&ada, (void*)&out, (void*)&mbox };
    hipLaunchCooperativeKernel((const void*)net_kernel, dim3(T_DIM), dim3(NTHREADS),
                               args, 0, stream);
}

// Round 6
// 417.792 us; speedup vs baseline: 1.2018x; 1.0229x over previous
//
#include <hip/hip_runtime.h>
#include <math.h>

#define L_DIM 8
#define T_DIM 128
#define S_DIM 128
#define SP1   129
#define SPAD  132                      // padded LDS row stride (16-B aligned)
#define BIGF  1000000000.0f
#define EPSF  1e-5f
#define NTHREADS 1024
#define NWAVES 16
#define NCHUNKS 132                    // staged n q,k: 2*128*SPAD floats / 256

// ---- DPP cross-lane reductions on the VALU pipe ----
template<int CTRL>
__device__ __forceinline__ float dpp_add_part(float x) {
    // shifted-in / non-receiving lanes contribute 0 (old=0, bound_ctrl=false)
    int r = __builtin_amdgcn_update_dpp(0, __float_as_int(x), CTRL, 0xF, 0xF, false);
    return __int_as_float(r);
}
// Sum over each 16-lane row; total lands in lane (li==15) of each group.
__device__ __forceinline__ float dpp16Sum15(float x) {
    x += dpp_add_part<0x111>(x);  // row_shr:1
    x += dpp_add_part<0x112>(x);  // row_shr:2
    x += dpp_add_part<0x114>(x);  // row_shr:4
    x += dpp_add_part<0x118>(x);  // row_shr:8
    return x;
}
// Sum over 64 lanes; total lands in lane 63.
__device__ __forceinline__ float dppSum63(float x) {
    x += dpp_add_part<0x111>(x);
    x += dpp_add_part<0x112>(x);
    x += dpp_add_part<0x114>(x);
    x += dpp_add_part<0x118>(x);
    x += dpp_add_part<0x142>(x);  // row_bcast:15
    x += dpp_add_part<0x143>(x);  // row_bcast:31
    return x;
}
__device__ __forceinline__ float lane63(float x) {
    return __int_as_float(__builtin_amdgcn_readlane(__float_as_int(x), 63));
}

// ---- raw barriers (no vmcnt drain except where stated) ----
__device__ __forceinline__ void wg_bar() {
    asm volatile("s_waitcnt lgkmcnt(0)" ::: "memory");
    __builtin_amdgcn_s_barrier();
    asm volatile("" ::: "memory");
}
__device__ __forceinline__ void wg_bar_vm() {
    asm volatile("s_waitcnt vmcnt(0) lgkmcnt(0)" ::: "memory");
    __builtin_amdgcn_s_barrier();
    asm volatile("" ::: "memory");
}

// async global->LDS, 16B per lane (global_load_lds_dwordx4); counts on vmcnt
__device__ __forceinline__ void gld_lds16(const float* g, float* l) {
    __builtin_amdgcn_global_load_lds(
        (const __attribute__((address_space(1))) void*)g,
        (__attribute__((address_space(3))) void*)l,
        16, 0, 0);
}

// Stage attn_n[b][t] q,k (2 x 128 rows x 129 floats) into LDS with rows PADDED
// to 132 floats. LDS dest is linear (wave-uniform base + lane*16B); padding is
// achieved by pre-swizzling the per-lane GLOBAL source address. Pad cols
// 129..131 hold in-bounds garbage (next row / v-matrix) and are never consumed.
// Zero VGPR cost for the payload: data never touches registers.
__device__ __forceinline__ void stage_nqk(const float* __restrict__ src,
                                          float* __restrict__ lds,
                                          int wid, int lane) {
#pragma unroll
    for (int k = 0; k < 9; ++k) {
        int c = wid + k * NWAVES;
        if (c < NCHUNKS) {
            int s   = c * 64 + lane;      // 16-B slot id; 33 slots per padded row
            int row = s / 33;
            int w   = s - row * 33;
            gld_lds16(src + (size_t)row * SP1 + w * 4, lds + c * 256);
        }
    }
}

// matvec rows r_base, r_base+4 straight from GLOBAL (L2/L3-resident attn_t).
// With 16-lane groups the WG covers all 128 rows exactly once: no redundancy.
__device__ __forceinline__ void mv_glb(const float* __restrict__ mat,
                                       const float in[8], int li, int r_base,
                                       float* __restrict__ dst) {
#pragma unroll
    for (int p = 0; p < 2; ++p) {
        int r = r_base + p * 4;
        const float* row = mat + (size_t)r * SP1;
        float acc = 0.0f;
#pragma unroll
        for (int e = 0; e < 8; ++e) acc = fmaf(row[li * 8 + e], in[e], acc);
        acc = dpp16Sum15(acc);
        if (li == 15) dst[r] = acc + row[128];
    }
}

// matvec from the padded staged-LDS matrix (stride SPAD, 16-B aligned rows)
__device__ __forceinline__ void mv_stage(const float* __restrict__ mat,
                                         const float in[8], int li, int r_base,
                                         float* __restrict__ dst) {
#pragma unroll
    for (int p = 0; p < 2; ++p) {
        int r = r_base + p * 4;
        const float* row = mat + r * SPAD;
        float acc = 0.0f;
#pragma unroll
        for (int e = 0; e < 8; ++e) acc = fmaf(row[li * 8 + e], in[e], acc);
        acc = dpp16Sum15(acc);
        if (li == 15) dst[r] = acc + row[128];
    }
}

// matvec from register-held rows (n-attn v only: 18 persistent VGPRs)
__device__ __forceinline__ void mv_regs(const float wv[2][8], const float wb[2],
                                        const float in[8], int li, int r_base,
                                        float* __restrict__ dst) {
#pragma unroll
    for (int p = 0; p < 2; ++p) {
        float acc = 0.0f;
#pragma unroll
        for (int e = 0; e < 8; ++e) acc = fmaf(wv[p][e], in[e], acc);
        acc = dpp16Sum15(acc);
        if (li == 15) dst[r_base + p * 4] = acc + wb[p];
    }
}

// prefetch one 128x129 matrix's 2 rows into regs
__device__ __forceinline__ void row_prefetch(const float* __restrict__ mb_,
                                             int li, int r0, int r1,
                                             float arr[2][8], float* b0, float* b1) {
#pragma unroll
    for (int p = 0; p < 2; ++p) {
        int r = p ? r1 : r0;
        const float* row = mb_ + (size_t)r * SP1 + li * 8;
#pragma unroll
        for (int e = 0; e < 8; ++e) arr[p][e] = row[e];
        float bb = mb_[(size_t)r * SP1 + 128];
        if (p) *b1 = bb; else *b0 = bb;
    }
}

// t-softmax + @v + residual; group (wid,g) owns rows r_base, r_base+4.
// No max-reduction (unmasked scores are row-shift-invariant; exp of bounded qk).
__device__ __forceinline__ void attn_sm_t(int li, int r_base,
                                          const float* __restrict__ lds_q,
                                          const float* __restrict__ lds_k,
                                          const float* __restrict__ lds_v,
                                          const float* __restrict__ resid,
                                          float* __restrict__ lds_out)
{
    const float scale = 0.08838834764831845f; // rsqrt(128)
    float kx[8], vx[8];
#pragma unroll
    for (int e = 0; e < 8; ++e) { kx[e] = lds_k[li * 8 + e]; vx[e] = lds_v[li * 8 + e]; }
#pragma unroll
    for (int p = 0; p < 2; ++p) {
        int r = r_base + p * 4;
        float qs = lds_q[r] * scale;
        float den = 0.0f, num = 0.0f;
#pragma unroll
        for (int e = 0; e < 8; ++e) {
            float ee = __expf(qs * kx[e]);
            den += ee;
            num = fmaf(ee, vx[e], num);
        }
        den = dpp16Sum15(den);
        num = dpp16Sum15(num);
        if (li == 15) lds_out[r] = num / den + resid[r];
    }
}

__global__ __launch_bounds__(NTHREADS)
void net_kernel(const float* __restrict__ x,
                const float* __restrict__ W,
                const float* __restrict__ maskp,
                const float* __restrict__ attn_t,
                const float* __restrict__ attn_n,
                const float* __restrict__ norm_params,
                const float* __restrict__ ada,
                float* __restrict__ out,
                unsigned long long* __restrict__ mbox)
{
    const int t    = blockIdx.x;
    const int tid  = threadIdx.x;
    const int lane = tid & 63;
    const int wid  = tid >> 6;
    const int li   = lane & 15;
    const int g    = lane >> 4;
    const int r0   = wid * 8 + g;
    const int r1   = r0 + 4;

    __shared__ float lds_nqk[2 * S_DIM * SPAD];  // staged attn_n q,k (132 KiB)
    __shared__ float lds_vals[S_DIM];            // LN'd input (written by wave 0)
    __shared__ float lds_q[S_DIM], lds_k[S_DIM], lds_v[S_DIM];
    __shared__ float lds_tv[S_DIM];
    __shared__ float lds_aff[NWAVES];

    float nv[2][8];                              // n-attn v rows: the ONLY big
    float nvb0, nvb1;                            // persistent register state

    // ---- prologue: stage attn_n[0][t] q,k; prefetch its v rows ----
    {
        const float* srcn = attn_n + (size_t)t * 3 * S_DIM * SP1;
        stage_nqk(srcn, lds_nqk, wid, lane);
        row_prefetch(srcn + 2 * S_DIM * SP1, li, r0, r1, nv, &nvb0, &nvb1);
    }

    for (int b = 0; b < L_DIM; ++b) {
        // ---- per-layer aux loads (L2/L3-resident; land during the poll window) ----
        const float* mrow = maskp + (size_t)(b * T_DIM + t) * S_DIM;
        const float* wrow = W + (size_t)(b * T_DIM + t) * SP1;
        float m1mj[8];
#pragma unroll
        for (int e = 0; e < 8; ++e) m1mj[e] = 1.0f - mrow[li * 8 + e];
        float mr0 = mrow[r0], mr1 = mrow[r1];
        float wr0 = wrow[r0], wr1 = wrow[r1];
        float wb  = (wid == 0) ? wrow[128] : 0.0f;

        // ---- 1+2: poll + gelu + LayerNorm — WAVE 0 ONLY (single poller per WG:
        //      16x less agent-scope load traffic hammering the 1 KB mailbox line
        //      set at the LLC; the other 15 waves sleep at BAR_A, freeing the
        //      SIMDs for wave 0's serial chain). LN is intra-wave (dppSum63). ----
        if (wid == 0) {
            float np00 = norm_params[(b * 2 + 0) * S_DIM + lane];
            float np10 = norm_params[(b * 2 + 0) * S_DIM + lane + 64];
            float np01 = norm_params[(b * 2 + 1) * S_DIM + lane];
            float np11 = norm_params[(b * 2 + 1) * S_DIM + lane + 64];
            float v0, v1;
            if (b == 0) {
                v0 = x[lane]; v1 = x[lane + 64];
            } else {
                float a00 = ada[((b - 1) * T_DIM + lane) * 2 + 0];
                float a01 = ada[((b - 1) * T_DIM + lane) * 2 + 1];
                float a10 = ada[((b - 1) * T_DIM + lane + 64) * 2 + 0];
                float a11 = ada[((b - 1) * T_DIM + lane + 64) * 2 + 1];
                const unsigned long long* mb_ = mbox + (size_t)(b - 1) * T_DIM;
                unsigned long long u0, u1;
                do {  // combined poll: one loop, both words
                    u0 = __hip_atomic_load(&mb_[lane], __ATOMIC_RELAXED, __HIP_MEMORY_SCOPE_AGENT);
                    u1 = __hip_atomic_load(&mb_[lane + 64], __ATOMIC_RELAXED, __HIP_MEMORY_SCOPE_AGENT);
                } while ((unsigned int)(u0 >> 32) != (unsigned int)b ||
                         (unsigned int)(u1 >> 32) != (unsigned int)b);
                {
                    float z = __uint_as_float((unsigned int)u0) * a00;
                    float z3 = z * z * z;
                    v0 = 0.5f * z * (1.0f + tanhf(0.7978845608028654f * (z + 0.044715f * z3))) * a01;
                }
                {
                    float z = __uint_as_float((unsigned int)u1) * a10;
                    float z3 = z * z * z;
                    v1 = 0.5f * z * (1.0f + tanhf(0.7978845608028654f * (z + 0.044715f * z3))) * a11;
                }
            }
            float s  = dppSum63(v0 + v1);
            float mu = lane63(s) * (1.0f / 128.0f);
            float d0 = v0 - mu, d1 = v1 - mu;
            float s2 = dppSum63(fmaf(d0, d0, d1 * d1));
            float rstd = rsqrtf(lane63(s2) * (1.0f / 128.0f) + EPSF);
            lds_vals[lane]      = d0 * rstd * np00 + np01;
            lds_vals[lane + 64] = d1 * rstd * np10 + np11;
        }
        wg_bar(); // BAR_A: lds_vals ready

        // ---- 3: t-attention qkv — rows straight from L2 (each row read exactly
        //      once per WG; no staging, no long-lived regs) ----
        {
            float iv[8];
#pragma unroll
            for (int e = 0; e < 8; ++e) iv[e] = lds_vals[li * 8 + e];
            const float* bb = attn_t + (size_t)b * 3 * S_DIM * SP1;
            mv_glb(bb,                    iv, li, r0, lds_q);
            mv_glb(bb + 1 * S_DIM * SP1,  iv, li, r0, lds_k);
            mv_glb(bb + 2 * S_DIM * SP1,  iv, li, r0, lds_v);
        }
        wg_bar(); // BAR_B

        // ---- 4: t-softmax (unmasked) + residual ----
        attn_sm_t(li, r0, lds_q, lds_k, lds_v, lds_vals, lds_tv);
        wg_bar_vm(); // BAR_C: the one vmcnt drain — staged n q,k for b now visible

        // ---- 5: n-attention qkv: q,k from staged LDS, v from regs ----
        {
            float tvv[8];
#pragma unroll
            for (int e = 0; e < 8; ++e) tvv[e] = lds_tv[li * 8 + e];
            mv_stage(lds_nqk,                 tvv, li, r0, lds_q);
            mv_stage(lds_nqk + S_DIM * SPAD,  tvv, li, r0, lds_k);
            float bv[2] = { nvb0, nvb1 };
            mv_regs(nv, bv, tvv, li, r0, lds_v);
        }
        wg_bar(); // BAR_D: n-qkv visible; lds_nqk readers done -> safe to restage

        // ---- stage layer b+1's n q,k + prefetch its v rows; in flight across
        //      n-softmax, aff, publish, poll, LN, t-attn -> drained at BAR_C(b+1)
        if (b < L_DIM - 1) {
            const float* srcn = attn_n + (size_t)((b + 1) * T_DIM + t) * 3 * S_DIM * SP1;
            stage_nqk(srcn, lds_nqk, wid, lane);
            row_prefetch(srcn + 2 * S_DIM * SP1, li, r0, r1, nv, &nvb0, &nvb1);
        }

        // ---- 6: n-softmax (masked) + residual, FUSED with aff partial ----
        {
            const float scale = 0.08838834764831845f;
            float kx[8], vx[8];
#pragma unroll
            for (int e = 0; e < 8; ++e) { kx[e] = lds_k[li * 8 + e]; vx[e] = lds_v[li * 8 + e]; }
            float o0 = 0.0f, o1 = 0.0f;
#pragma unroll
            for (int p = 0; p < 2; ++p) {
                int r = r0 + p * 4;
                float qs = lds_q[r] * scale;
                float bp = BIGF * (p ? mr1 : mr0);
                float den = 0.0f, num = 0.0f;
#pragma unroll
                for (int e = 0; e < 8; ++e) {
                    float s_ = fmaf(-bp, m1mj[e], qs * kx[e]);
                    float ee = __expf(s_);
                    den += ee;
                    num = fmaf(ee, vx[e], num);
                }
                den = dpp16Sum15(den);
                num = dpp16Sum15(num);
                float o = num / den + lds_tv[r];  // valid in owner lane li==15
                if (p) o1 = o; else o0 = o;
            }
            // aff partial: vn feeds ONLY the einsum -> fold it here, skip lds_vn
            float part = (li == 15) ? (wr0 * mr0 * o0 + wr1 * mr1 * o1) : 0.0f;
            part = dppSum63(part);
            if (lane == 63) lds_aff[wid] = part;
        }
        wg_bar(); // BAR_E

        // ---- 7: final aff reduce + publish (wave 0; others run ahead) ----
        if (wid == 0) {
            float pa = (lane < NWAVES) ? lds_aff[lane] : 0.0f;
            pa = dppSum63(pa);
            if (lane == 63) {
                float aff = pa + wb;
                if (b == L_DIM - 1) {
                    out[t] = aff;
                } else {
                    unsigned long long u =
                        ((unsigned long long)(unsigned int)(b + 1) << 32) |
                        (unsigned long long)__float_as_uint(aff);
                    __hip_atomic_store(&mbox[(size_t)b * T_DIM + t], u,
                                       __ATOMIC_RELAXED, __HIP_MEMORY_SCOPE_AGENT);
                }
            }
        }
        // lds_vals WAR: wave0 rewrites it only in step 1+2 of b+1, after BAR_E(b);
        // all reads of lds_vals(b) (t-qkv, t-softmax resid) completed before
        // BAR_C(b). lds_aff WAR: rewritten only after BAR_D(b+1).
    }
}

extern "C" void kernel_launch(void* const* d_in, const int* in_sizes, int n_in,
                              void* d_out, int out_size, void* d_ws, size_t ws_size,
                              hipStream_t stream) {
    const float* x           = (const float*)d_in[0];
    const float* W           = (const float*)d_in[1];
    const float* maskp       = (const float*)d_in[2];
    const float* attn_t      = (const float*)d_in[3];
    const float* attn_n      = (const float*)d_in[4];
    // d_in[5] = attn_mask_n (67 MB) intentionally unused: recomputed from mask
    const float* norm_params = (const float*)d_in[6];
    const float* ada         = (const float*)d_in[7];
    float* out = (float*)d_out;

    unsigned long long* mbox = (unsigned long long*)d_ws; // 7 epochs x 128 slots x 8B

    hipMemsetAsync(d_ws, 0, (size_t)(L_DIM - 1) * T_DIM * sizeof(unsigned long long), stream);

    void* args[] = { (void*)&x, (void*)&W, (void*)&maskp, (void*)&attn_t, (void*)&attn_n,
                     (void*)&norm_params, (void*)&ada, (void*)&out, (void*)&mbox };
    hipLaunchCooperativeKernel((const void*)net_kernel, dim3(T_DIM), dim3(NTHREADS),
                               args, 0, stream);
}